// Round 1
// baseline (254.962 us; speedup 1.0000x reference)
//
#include <hip/hip_runtime.h>
#include <math.h>

#define BSZ  16
#define DIM  768
#define SEQA 1024
#define SEQB 1024

typedef float f32x4 __attribute__((ext_vector_type(4)));
typedef long long llong;

__device__ inline void gload_lds16(const void* g, void* l) {
    __builtin_amdgcn_global_load_lds(
        (const __attribute__((address_space(1))) void*)g,
        (__attribute__((address_space(3))) void*)l, 16, 0, 0);
}

// ---- float <-> order-preserving uint key (atomicMax on floats) ----
__device__ inline unsigned enc_key(float f) {
    unsigned u = __float_as_uint(f);
    return (u & 0x80000000u) ? ~u : (u | 0x80000000u);
}
__device__ inline float dec_key(unsigned k) {
    return (k & 0x80000000u) ? __uint_as_float(k ^ 0x80000000u) : __uint_as_float(~k);
}

// ---- fp8 e4m3 (OCP) pack helpers ----
__device__ inline unsigned pk4_fp8(float a, float b, float c, float d) {
    int v = 0;
    v = __builtin_amdgcn_cvt_pk_fp8_f32(a, b, v, false);
    v = __builtin_amdgcn_cvt_pk_fp8_f32(c, d, v, true);
    return (unsigned)v;
}
__device__ inline unsigned char f2fp8(float a) {
    return (unsigned char)(__builtin_amdgcn_cvt_pk_fp8_f32(a, a, 0, false) & 0xFF);
}

// tanh via hardware exp: exact 1.0f in saturation, ~1e-6 error mid-range
__device__ inline float fast_tanh(float x) {
    float ax = fabsf(x);
    float u = __expf(-2.0f * ax);
    float th = __fdividef(1.0f - u, 1.0f + u);
    return copysignf(th, x);
}

// ---- prepass: X[b][DIM][SEQ] f32 -> Xt[b][SEQ][DIM] fp8 for A (z<16) and B (z>=16) ----
__global__ __launch_bounds__(256) void t_cast_AB(const float* __restrict__ A,
                                                 const float* __restrict__ B,
                                                 unsigned char* __restrict__ At,
                                                 unsigned char* __restrict__ Bt) {
    __shared__ float tl[64][68];
    const int z = blockIdx.z;
    const float* X = (z < BSZ) ? A : B;
    unsigned char* Y = (z < BSZ) ? At : Bt;
    const int b = z & 15;
    const int d0 = blockIdx.y * 64;
    const int s0 = blockIdx.x * 64;
    const int tid = threadIdx.x;
    const int rr = tid >> 4, c4 = tid & 15;  // float4 loader coords
    const float* Xb = X + ((size_t)b * DIM + d0) * SEQA + s0;
#pragma unroll
    for (int i = 0; i < 4; i++) {
        int row = i * 16 + rr;
        float4 v = *(const float4*)&Xb[(size_t)row * SEQA + c4 * 4];
        *(float4*)&tl[row][c4 * 4] = v;
    }
    __syncthreads();
    unsigned char* Yb = Y + ((size_t)b * SEQA + s0) * DIM + d0;
    const int m = tid & 15, sl = tid >> 4;
#pragma unroll
    for (int i = 0; i < 4; i++) {
        int s = sl + 16 * i;
        unsigned v = pk4_fp8(tl[4 * m + 0][s], tl[4 * m + 1][s], tl[4 * m + 2][s], tl[4 * m + 3][s]);
        *(unsigned*)&Yb[(size_t)s * DIM + 4 * m] = v;
    }
}

// ---- prepass: U[d][e] f32 -> Ut[e][d] fp8 ; also init max-keys ----
__global__ __launch_bounds__(256) void t_cast_U(const float* __restrict__ U,
                                                unsigned char* __restrict__ Ut,
                                                unsigned* __restrict__ keyA,
                                                unsigned* __restrict__ keyB) {
    __shared__ float tl[64][68];
    const int d0 = blockIdx.y * 64;
    const int e0 = blockIdx.x * 64;
    const int tid = threadIdx.x;
    const int bid = blockIdx.y * gridDim.x + blockIdx.x;
    if (bid < 64) {
        int i = bid * 256 + tid;
        keyA[i] = 0u;
        keyB[i] = 0u;
    }
    const int rr = tid >> 4, c4 = tid & 15;
#pragma unroll
    for (int i = 0; i < 4; i++) {
        int row = i * 16 + rr;
        float4 v = *(const float4*)&U[(size_t)(d0 + row) * DIM + e0 + c4 * 4];
        *(float4*)&tl[row][c4 * 4] = v;
    }
    __syncthreads();
    const int m = tid & 15, sl = tid >> 4;
#pragma unroll
    for (int i = 0; i < 4; i++) {
        int e = sl + 16 * i;
        unsigned v = pk4_fp8(tl[4 * m + 0][e], tl[4 * m + 1][e], tl[4 * m + 2][e], tl[4 * m + 3][e]);
        *(unsigned*)&Ut[(size_t)(e0 + e) * DIM + d0 + 4 * m] = v;
    }
}

// Stage one tile (rows of `src`, pitch DIM, 128 bytes of K) into LDS with granule-XOR
// swizzle. Wave `wid` covers rows [wid*32, wid*32+32). 4 gload_lds per wave per call.
__device__ inline void stage_tile(const unsigned char* __restrict__ src, int row0,
                                  int kbyte0, unsigned char* lds, int wid, int lane) {
    const int r8 = lane >> 3;              // row within 8-row group
    const int g  = lane & 7;               // dest granule slot
    const int gg = g ^ (r8 & 7);           // source granule (XOR swizzle)
#pragma unroll
    for (int t = 0; t < 4; ++t) {
        int row = row0 + wid * 32 + t * 8 + r8;
        gload_lds16(src + (size_t)row * DIM + kbyte0 + gg * 16,
                    lds + (wid * 32 + t * 8) * 128 + lane * 16);
    }
}

// Read an 8-byte fp8 fragment (16 rows x k-slice) with matching XOR un-swizzle.
// rowbase multiple of 16; h = 32-byte k-slice index (0..3).
__device__ inline llong frag_read(const unsigned char* lds, int rowbase, int l15,
                                  int quad, int h) {
    int gg = 2 * h + (quad >> 1);
    int off = (rowbase + l15) * 128 + ((gg ^ (l15 & 7)) << 4) + (quad & 1) * 8;
    return *(const llong*)(lds + off);
}

#define TB (256 * 128)  // one 256-row x 128-byte LDS tile

// One BK=128 K-tile of MFMA for the 256x256 / 8-wave geometry.
// Ms = M-side LDS tile (rows wr*128 + 16i), Ns = N-side (rows wc*64 + 16j).
__device__ __forceinline__ void ktile_mfma(const unsigned char* Ms, const unsigned char* Ns,
                                           int wr, int wc, int l15, int quad,
                                           f32x4 (&acc)[8][4]) {
#pragma unroll
    for (int h = 0; h < 4; ++h) {
        llong av[8], bv[4];
#pragma unroll
        for (int i = 0; i < 8; ++i) av[i] = frag_read(Ms, wr * 128 + 16 * i, l15, quad, h);
#pragma unroll
        for (int j = 0; j < 4; ++j) bv[j] = frag_read(Ns, wc * 64 + 16 * j, l15, quad, h);
#pragma unroll
        for (int i = 0; i < 8; ++i)
#pragma unroll
            for (int j = 0; j < 4; ++j)
                acc[i][j] = __builtin_amdgcn_mfma_f32_16x16x32_fp8_fp8(av[i], bv[j], acc[i][j], 0, 0, 0);
    }
}

// Depth-2 counted-vmcnt K-loop: 2 LDS buffers, 2 raw barriers/iter, vmcnt(8)
// (= next tile's 8 loads stay in flight across barriers), drain only on last iter.
#define KLOOP(MSRC, NSRC, MS, NS)                                                   \
    stage_tile(MSRC, 0, 0, MS, wid, lane);                                          \
    stage_tile(NSRC, 0, 0, NS, wid, lane);                                          \
    stage_tile(MSRC, 0, 128, MS + TB, wid, lane);                                   \
    stage_tile(NSRC, 0, 128, NS + TB, wid, lane);                                   \
    _Pragma("unroll")                                                               \
    for (int kt = 0; kt < DIM / 128; ++kt) {                                        \
        if (kt < DIM / 128 - 1) asm volatile("s_waitcnt vmcnt(8)" ::: "memory");    \
        else                    asm volatile("s_waitcnt vmcnt(0)" ::: "memory");    \
        __builtin_amdgcn_s_barrier();                                               \
        asm volatile("" ::: "memory");                                              \
        __builtin_amdgcn_s_setprio(1);                                              \
        ktile_mfma(MS + (kt & 1) * TB, NS + (kt & 1) * TB, wr, wc, l15, quad, acc); \
        __builtin_amdgcn_s_setprio(0);                                              \
        asm volatile("s_waitcnt lgkmcnt(0)" ::: "memory");                          \
        __builtin_amdgcn_s_barrier();                                               \
        asm volatile("" ::: "memory");                                              \
        if (kt + 2 < DIM / 128) {                                                   \
            stage_tile(MSRC, 0, (kt + 2) * 128, MS + (kt & 1) * TB, wid, lane);     \
            stage_tile(NSRC, 0, (kt + 2) * 128, NS + (kt & 1) * TB, wid, lane);     \
        }                                                                           \
    }

// ---- k1: Ct[b][s][e] = sum_d At[b][s][d] * Ut[e][d]  (fp8 MFMA, 256x256, BK=128) ----
// A-side = At (M=s), B-side = Ut (N=e). 8 waves: wr in {0,1} x 128 s-rows, wc in {0..3} x 64 e-cols.
__global__ __launch_bounds__(512, 2) void k1_ua(const unsigned char* __restrict__ At,
                                                const unsigned char* __restrict__ Ut,
                                                unsigned char* __restrict__ Ct) {
    __shared__ __align__(16) unsigned char As[2 * TB];
    __shared__ __align__(16) unsigned char Us[2 * TB];
    const int b  = blockIdx.z;
    const int s0 = blockIdx.x * 256;
    const int e0 = blockIdx.y * 256;
    const int tid = threadIdx.x;
    const int lane = tid & 63;
    const int wid = tid >> 6;
    const int wr = wid >> 2, wc = wid & 3;
    const int quad = lane >> 4, l15 = lane & 15;

    const unsigned char* Atb = At + ((size_t)b * SEQA + s0) * DIM;
    const unsigned char* Utb = Ut + (size_t)e0 * DIM;

    f32x4 acc[8][4] = {};

    KLOOP(Atb, Utb, As, Us)

    // D: M(s) = wr*128+16i+quad*4+r, N(e) = wc*64+16j+l15
    unsigned char* Cb = Ct + (size_t)b * SEQA * DIM;
#pragma unroll
    for (int i = 0; i < 8; ++i)
#pragma unroll
        for (int j = 0; j < 4; ++j) {
            int e_g = e0 + wc * 64 + 16 * j + l15;
#pragma unroll
            for (int r = 0; r < 4; ++r) {
                int s_g = s0 + wr * 128 + 16 * i + quad * 4 + r;
                Cb[(size_t)s_g * DIM + e_g] = f2fp8(acc[i][j][r]);
            }
        }
}

// ---- k2: align^T tile = tanh(Bt x Ct) + msk; fused max -> atomic keys ----
// A-side = Bt (M=t), B-side = Ct (N=s). Mask loaded in epilogue (VGPR budget).
__global__ __launch_bounds__(512, 2) void k2_align(const unsigned char* __restrict__ Ct,
                                                   const unsigned char* __restrict__ Bt,
                                                   const float* __restrict__ msk,
                                                   unsigned* __restrict__ keyA,
                                                   unsigned* __restrict__ keyB) {
    __shared__ __align__(16) unsigned char Cs[2 * TB];
    __shared__ __align__(16) unsigned char Bs[2 * TB];
    const int b  = blockIdx.z;
    const int t0 = blockIdx.x * 256;
    const int s0 = blockIdx.y * 256;
    const int tid = threadIdx.x;
    const int lane = tid & 63;
    const int wid = tid >> 6;
    const int wr = wid >> 2, wc = wid & 3;
    const int quad = lane >> 4, l15 = lane & 15;

    const unsigned char* Btb = Bt + ((size_t)b * SEQB + t0) * DIM;
    const unsigned char* Ctb = Ct + ((size_t)b * SEQA + s0) * DIM;

    f32x4 acc[8][4] = {};

    KLOOP(Btb, Ctb, Bs, Cs)

    // epilogue: tanh + mask (16 rows x 64B contiguous per load instruction)
    const float* Mb = msk + (size_t)b * SEQA * SEQB;
#pragma unroll
    for (int i = 0; i < 8; ++i)
#pragma unroll
        for (int j = 0; j < 4; ++j) {
            int s_g = s0 + wc * 64 + 16 * j + l15;
            int t_g = t0 + wr * 128 + 16 * i + quad * 4;
            float4 mvv = *(const float4*)&Mb[(size_t)s_g * SEQB + t_g];
            acc[i][j][0] = fast_tanh(acc[i][j][0]) + mvv.x;
            acc[i][j][1] = fast_tanh(acc[i][j][1]) + mvv.y;
            acc[i][j][2] = fast_tanh(acc[i][j][2]) + mvv.z;
            acc[i][j][3] = fast_tanh(acc[i][j][3]) + mvv.w;
        }
    // keyA[s]: max over t (in-lane i,r; cross-quad)
#pragma unroll
    for (int j = 0; j < 4; ++j) {
        float m = -INFINITY;
#pragma unroll
        for (int i = 0; i < 8; ++i)
#pragma unroll
            for (int r = 0; r < 4; ++r) m = fmaxf(m, acc[i][j][r]);
        m = fmaxf(m, __shfl_xor(m, 16));
        m = fmaxf(m, __shfl_xor(m, 32));
        if (quad == 0)
            atomicMax(&keyA[b * SEQA + s0 + wc * 64 + 16 * j + l15], enc_key(m));
    }
    // keyB[t]: max over s (in-lane j; cross-l15)
#pragma unroll
    for (int i = 0; i < 8; ++i)
#pragma unroll
        for (int r = 0; r < 4; ++r) {
            float m = fmaxf(fmaxf(acc[i][0][r], acc[i][1][r]), fmaxf(acc[i][2][r], acc[i][3][r]));
            m = fmaxf(m, __shfl_xor(m, 1));
            m = fmaxf(m, __shfl_xor(m, 2));
            m = fmaxf(m, __shfl_xor(m, 4));
            m = fmaxf(m, __shfl_xor(m, 8));
            if (l15 == 0)
                atomicMax(&keyB[b * SEQB + t0 + wr * 128 + 16 * i + quad * 4 + r], enc_key(m));
        }
}

// ---- k3: softmax over per-token maxes ----
__global__ __launch_bounds__(256) void k3_softmax(const unsigned* __restrict__ keyA,
                                                  const unsigned* __restrict__ keyB,
                                                  float* __restrict__ scoreA,
                                                  float* __restrict__ scoreB) {
    const int b = blockIdx.x;
    const bool isA = (blockIdx.y == 0);
    const unsigned* keys = isA ? (keyA + b * SEQA) : (keyB + b * SEQB);
    float* score = isA ? (scoreA + b * SEQA) : (scoreB + b * SEQB);
    __shared__ float sh[4];
    const int tid = threadIdx.x;
    float m[4];
    float mx = -INFINITY;
#pragma unroll
    for (int k = 0; k < 4; k++) {
        m[k] = dec_key(keys[tid + 256 * k]);
        mx = fmaxf(mx, m[k]);
    }
#pragma unroll
    for (int o = 32; o > 0; o >>= 1) mx = fmaxf(mx, __shfl_down(mx, o, 64));
    if ((tid & 63) == 0) sh[tid >> 6] = mx;
    __syncthreads();
    mx = fmaxf(fmaxf(sh[0], sh[1]), fmaxf(sh[2], sh[3]));
    __syncthreads();
    float e[4];
    float sum = 0.f;
#pragma unroll
    for (int k = 0; k < 4; k++) { e[k] = expf(m[k] - mx); sum += e[k]; }
#pragma unroll
    for (int o = 32; o > 0; o >>= 1) sum += __shfl_down(sum, o, 64);
    if ((tid & 63) == 0) sh[tid >> 6] = sum;
    __syncthreads();
    sum = sh[0] + sh[1] + sh[2] + sh[3];
    float inv = 1.0f / sum;
#pragma unroll
    for (int k = 0; k < 4; k++) score[tid + 256 * k] = e[k] * inv;
}

// ---- k4: out[b,d] = sum_s X[b,d,s] * score[b,s]  (fp32, one wave per row) ----
__global__ __launch_bounds__(256) void k4_out(const float* __restrict__ A,
                                              const float* __restrict__ B,
                                              const float* __restrict__ scoreA,
                                              const float* __restrict__ scoreB,
                                              float* __restrict__ out) {
    const int which = blockIdx.y;
    const int row = blockIdx.x * 4 + (threadIdx.x >> 6);
    const int lane = threadIdx.x & 63;
    const float* X = which ? B : A;
    const float* S = which ? scoreB : scoreA;
    const int b = row / DIM;
    const float4* xr = (const float4*)(X + (size_t)row * SEQA);
    const float4* sr = (const float4*)(S + (size_t)b * SEQA);
    float acc = 0.f;
#pragma unroll
    for (int q = lane; q < SEQA / 4; q += 64) {
        float4 x = xr[q];
        float4 s = sr[q];
        acc += x.x * s.x + x.y * s.y + x.z * s.z + x.w * s.w;
    }
#pragma unroll
    for (int o = 32; o > 0; o >>= 1) acc += __shfl_down(acc, o, 64);
    if (lane == 0) out[which * (BSZ * DIM) + row] = acc;
}

extern "C" void kernel_launch(void* const* d_in, const int* in_sizes, int n_in,
                              void* d_out, int out_size, void* d_ws, size_t ws_size,
                              hipStream_t stream) {
    const float* A   = (const float*)d_in[0];  // (16,768,1024)
    const float* B   = (const float*)d_in[1];  // (16,768,1024)
    const float* msk = (const float*)d_in[2];  // (16,1024,1024)
    const float* U   = (const float*)d_in[3];  // (768,768)
    float* out = (float*)d_out;

    char* ws = (char*)d_ws;
    unsigned char* At = (unsigned char*)ws;                   // 12,582,912
    unsigned char* Bt = (unsigned char*)(ws + 12582912);      // 12,582,912
    unsigned char* Ct = (unsigned char*)(ws + 25165824);      // 12,582,912
    unsigned char* Ut = (unsigned char*)(ws + 37748736);      //    589,824
    unsigned* keyA   = (unsigned*)(ws + 38338560);
    unsigned* keyB   = (unsigned*)(ws + 38404096);
    float*    scoreA = (float*)   (ws + 38469632);
    float*    scoreB = (float*)   (ws + 38535168);

    t_cast_U<<<dim3(DIM / 64, DIM / 64, 1), 256, 0, stream>>>(U, Ut, keyA, keyB);
    t_cast_AB<<<dim3(SEQA / 64, DIM / 64, 2 * BSZ), 256, 0, stream>>>(A, B, At, Bt);
    // 256^2 tiles, 8 waves, depth-2 counted-vmcnt pipeline
    k1_ua<<<dim3(SEQA / 256, DIM / 256, BSZ), 512, 0, stream>>>(At, Ut, Ct);
    k2_align<<<dim3(SEQB / 256, SEQA / 256, BSZ), 512, 0, stream>>>(Ct, Bt, msk, keyA, keyB);
    k3_softmax<<<dim3(BSZ, 2), 256, 0, stream>>>(keyA, keyB, scoreA, scoreB);
    k4_out<<<dim3(BSZ * DIM / 4, 2), 256, 0, stream>>>(A, B, scoreA, scoreB, out);
}

// Round 4
// 244.457 us; speedup vs baseline: 1.0430x; 1.0430x over previous
//
#include <hip/hip_runtime.h>
#include <math.h>

#define BSZ  16
#define DIM  768
#define SEQA 1024
#define SEQB 1024

typedef float f32x4 __attribute__((ext_vector_type(4)));
typedef long long llong;

__device__ inline void gload_lds16(const void* g, void* l) {
    __builtin_amdgcn_global_load_lds(
        (const __attribute__((address_space(1))) void*)g,
        (__attribute__((address_space(3))) void*)l, 16, 0, 0);
}

// ---- float <-> order-preserving uint key (atomicMax on floats) ----
__device__ inline unsigned enc_key(float f) {
    unsigned u = __float_as_uint(f);
    return (u & 0x80000000u) ? ~u : (u | 0x80000000u);
}
__device__ inline float dec_key(unsigned k) {
    return (k & 0x80000000u) ? __uint_as_float(k ^ 0x80000000u) : __uint_as_float(~k);
}

// ---- fp8 e4m3 (OCP) pack helpers ----
__device__ inline unsigned pk4_fp8(float a, float b, float c, float d) {
    int v = 0;
    v = __builtin_amdgcn_cvt_pk_fp8_f32(a, b, v, false);
    v = __builtin_amdgcn_cvt_pk_fp8_f32(c, d, v, true);
    return (unsigned)v;
}
__device__ inline unsigned char f2fp8(float a) {
    return (unsigned char)(__builtin_amdgcn_cvt_pk_fp8_f32(a, a, 0, false) & 0xFF);
}

// tanh via hardware exp: exact 1.0f in saturation, ~1e-6 error mid-range
__device__ inline float fast_tanh(float x) {
    float ax = fabsf(x);
    float u = __expf(-2.0f * ax);
    float th = __fdividef(1.0f - u, 1.0f + u);
    return copysignf(th, x);
}

// ---- prepass: X[b][DIM][SEQ] f32 -> Xt[b][SEQ][DIM] fp8 for A (z<16) and B (z>=16) ----
__global__ __launch_bounds__(256) void t_cast_AB(const float* __restrict__ A,
                                                 const float* __restrict__ B,
                                                 unsigned char* __restrict__ At,
                                                 unsigned char* __restrict__ Bt) {
    __shared__ float tl[64][68];
    const int z = blockIdx.z;
    const float* X = (z < BSZ) ? A : B;
    unsigned char* Y = (z < BSZ) ? At : Bt;
    const int b = z & 15;
    const int d0 = blockIdx.y * 64;
    const int s0 = blockIdx.x * 64;
    const int tid = threadIdx.x;
    const int rr = tid >> 4, c4 = tid & 15;  // float4 loader coords
    const float* Xb = X + ((size_t)b * DIM + d0) * SEQA + s0;
#pragma unroll
    for (int i = 0; i < 4; i++) {
        int row = i * 16 + rr;
        float4 v = *(const float4*)&Xb[(size_t)row * SEQA + c4 * 4];
        *(float4*)&tl[row][c4 * 4] = v;
    }
    __syncthreads();
    unsigned char* Yb = Y + ((size_t)b * SEQA + s0) * DIM + d0;
    const int m = tid & 15, sl = tid >> 4;
#pragma unroll
    for (int i = 0; i < 4; i++) {
        int s = sl + 16 * i;
        unsigned v = pk4_fp8(tl[4 * m + 0][s], tl[4 * m + 1][s], tl[4 * m + 2][s], tl[4 * m + 3][s]);
        *(unsigned*)&Yb[(size_t)s * DIM + 4 * m] = v;
    }
}

// ---- prepass: U[d][e] f32 -> Ut[e][d] fp8 ; also init max-keys ----
__global__ __launch_bounds__(256) void t_cast_U(const float* __restrict__ U,
                                                unsigned char* __restrict__ Ut,
                                                unsigned* __restrict__ keyA,
                                                unsigned* __restrict__ keyB) {
    __shared__ float tl[64][68];
    const int d0 = blockIdx.y * 64;
    const int e0 = blockIdx.x * 64;
    const int tid = threadIdx.x;
    const int bid = blockIdx.y * gridDim.x + blockIdx.x;
    if (bid < 64) {
        int i = bid * 256 + tid;
        keyA[i] = 0u;
        keyB[i] = 0u;
    }
    const int rr = tid >> 4, c4 = tid & 15;
#pragma unroll
    for (int i = 0; i < 4; i++) {
        int row = i * 16 + rr;
        float4 v = *(const float4*)&U[(size_t)(d0 + row) * DIM + e0 + c4 * 4];
        *(float4*)&tl[row][c4 * 4] = v;
    }
    __syncthreads();
    const int m = tid & 15, sl = tid >> 4;
#pragma unroll
    for (int i = 0; i < 4; i++) {
        int e = sl + 16 * i;
        unsigned v = pk4_fp8(tl[4 * m + 0][e], tl[4 * m + 1][e], tl[4 * m + 2][e], tl[4 * m + 3][e]);
        *(unsigned*)&Ut[(size_t)(e0 + e) * DIM + d0 + 4 * m] = v;
    }
}

// Stage a (nwaves*32)-row x 128-byte tile (rows of `src`, pitch DIM) into LDS with
// granule-XOR swizzle. Wave `wid` covers rows [wid*32, wid*32+32). 4 gloads/wave.
__device__ inline void stage_tile(const unsigned char* __restrict__ src, int row0,
                                  int kbyte0, unsigned char* lds, int wid, int lane) {
    const int r8 = lane >> 3;              // row within 8-row group
    const int g  = lane & 7;               // dest granule slot
    const int gg = g ^ (r8 & 7);           // source granule (XOR swizzle)
#pragma unroll
    for (int t = 0; t < 4; ++t) {
        int row = row0 + wid * 32 + t * 8 + r8;
        gload_lds16(src + (size_t)row * DIM + kbyte0 + gg * 16,
                    lds + (wid * 32 + t * 8) * 128 + lane * 16);
    }
}

// Read an 8-byte fp8 fragment (16 rows x k-slice) with matching XOR un-swizzle.
// rowbase multiple of 16; h = 32-byte k-slice index (0..3).
__device__ inline llong frag_read(const unsigned char* lds, int rowbase, int l15,
                                  int quad, int h) {
    int gg = 2 * h + (quad >> 1);
    int off = (rowbase + l15) * 128 + ((gg ^ (l15 & 7)) << 4) + (quad & 1) * 8;
    return *(const llong*)(lds + off);
}

// ---- k1: Ct[b][s][e] = sum_d At[b][s][d] * Ut[e][d]  (fp8 MFMA, 128x128, BK=128) ----
// Single-buffered 32KB LDS, 4 waves, 3 blocks/CU: cross-block overlap hides the
// barrier drains and the byte-store epilogue (m97/m114 regime).
__global__ __launch_bounds__(256, 3) void k1_ua(const unsigned char* __restrict__ At,
                                                const unsigned char* __restrict__ Ut,
                                                unsigned char* __restrict__ Ct) {
    __shared__ __align__(16) unsigned char As[128 * 128];
    __shared__ __align__(16) unsigned char Us[128 * 128];
    const int b  = blockIdx.z;
    const int s0 = blockIdx.x * 128;
    const int e0 = blockIdx.y * 128;
    const int tid = threadIdx.x;
    const int lane = tid & 63;
    const int wid = tid >> 6;
    const int wr = wid >> 1, wc = wid & 1;
    const int quad = lane >> 4, l15 = lane & 15;

    const unsigned char* Atb = At + (size_t)b * SEQA * DIM;
    f32x4 acc[4][4] = {};

    for (int d0 = 0; d0 < DIM; d0 += 128) {
        stage_tile(Atb + (size_t)s0 * DIM, 0, d0, As, wid, lane);
        stage_tile(Ut + (size_t)e0 * DIM, 0, d0, Us, wid, lane);
        __syncthreads();
#pragma unroll
        for (int h = 0; h < 4; ++h) {
            llong av[4], bv[4];
#pragma unroll
            for (int i = 0; i < 4; ++i) av[i] = frag_read(As, wr * 64 + 16 * i, l15, quad, h);
#pragma unroll
            for (int j = 0; j < 4; ++j) bv[j] = frag_read(Us, wc * 64 + 16 * j, l15, quad, h);
#pragma unroll
            for (int i = 0; i < 4; ++i)
#pragma unroll
                for (int j = 0; j < 4; ++j)
                    acc[i][j] = __builtin_amdgcn_mfma_f32_16x16x32_fp8_fp8(av[i], bv[j], acc[i][j], 0, 0, 0);
        }
        __syncthreads();
    }
    // D: M(s) = wr*64+16i+quad*4+r, N(e) = wc*64+16j+l15 -> byte stores, 16B segments
    unsigned char* Cb = Ct + (size_t)b * SEQA * DIM;
#pragma unroll
    for (int i = 0; i < 4; ++i)
#pragma unroll
        for (int j = 0; j < 4; ++j) {
            int e_g = e0 + wc * 64 + 16 * j + l15;
#pragma unroll
            for (int r = 0; r < 4; ++r) {
                int s_g = s0 + wr * 64 + 16 * i + quad * 4 + r;
                Cb[(size_t)s_g * DIM + e_g] = f2fp8(acc[i][j][r]);
            }
        }
}

// ---- k2: align^T tile = tanh(Bt x Ct) + msk; fused max -> atomic keys ----
// A-side = Bt (M=t), B-side = Ct (N=s). Mask loaded per-j in the EPILOGUE:
// keeps regs <=170 so 3 blocks/CU co-reside; the mask's HBM wait is hidden by
// the other blocks' K-loops instead of by prefetch registers.
__global__ __launch_bounds__(256, 3) void k2_align(const unsigned char* __restrict__ Ct,
                                                   const unsigned char* __restrict__ Bt,
                                                   const float* __restrict__ msk,
                                                   unsigned* __restrict__ keyA,
                                                   unsigned* __restrict__ keyB) {
    __shared__ __align__(16) unsigned char Cs[128 * 128];
    __shared__ __align__(16) unsigned char Bs[128 * 128];
    const int b  = blockIdx.z;
    const int t0 = blockIdx.x * 128;
    const int s0 = blockIdx.y * 128;
    const int tid = threadIdx.x;
    const int lane = tid & 63;
    const int wid = tid >> 6;
    const int wr = wid >> 1, wc = wid & 1;
    const int quad = lane >> 4, l15 = lane & 15;

    f32x4 acc[4][4] = {};

    for (int e0 = 0; e0 < DIM; e0 += 128) {
        stage_tile(Ct + (size_t)(b * SEQA + s0) * DIM, 0, e0, Cs, wid, lane);
        stage_tile(Bt + (size_t)(b * SEQB + t0) * DIM, 0, e0, Bs, wid, lane);
        __syncthreads();
#pragma unroll
        for (int h = 0; h < 4; ++h) {
            llong av[4], bv[4];
#pragma unroll
            for (int i = 0; i < 4; ++i) av[i] = frag_read(Bs, wr * 64 + 16 * i, l15, quad, h);
#pragma unroll
            for (int j = 0; j < 4; ++j) bv[j] = frag_read(Cs, wc * 64 + 16 * j, l15, quad, h);
#pragma unroll
            for (int i = 0; i < 4; ++i)
#pragma unroll
                for (int j = 0; j < 4; ++j)
                    acc[i][j] = __builtin_amdgcn_mfma_f32_16x16x32_fp8_fp8(av[i], bv[j], acc[i][j], 0, 0, 0);
        }
        __syncthreads();
    }

    // epilogue: per-j batched mask loads (4 float4 live at a time) + tanh
    const float* Mb = msk + (size_t)b * SEQA * SEQB;
#pragma unroll
    for (int j = 0; j < 4; ++j) {
        int s_g = s0 + wc * 64 + 16 * j + l15;
        float4 mvv[4];
#pragma unroll
        for (int i = 0; i < 4; ++i) {
            int t_g = t0 + wr * 64 + 16 * i + quad * 4;
            mvv[i] = *(const float4*)&Mb[(size_t)s_g * SEQB + t_g];
        }
#pragma unroll
        for (int i = 0; i < 4; ++i) {
            acc[i][j][0] = fast_tanh(acc[i][j][0]) + mvv[i].x;
            acc[i][j][1] = fast_tanh(acc[i][j][1]) + mvv[i].y;
            acc[i][j][2] = fast_tanh(acc[i][j][2]) + mvv[i].z;
            acc[i][j][3] = fast_tanh(acc[i][j][3]) + mvv[i].w;
        }
    }
    // keyA[s]: max over t (in-lane i,r; cross-quad)
#pragma unroll
    for (int j = 0; j < 4; ++j) {
        float m = -INFINITY;
#pragma unroll
        for (int i = 0; i < 4; ++i)
#pragma unroll
            for (int r = 0; r < 4; ++r) m = fmaxf(m, acc[i][j][r]);
        m = fmaxf(m, __shfl_xor(m, 16));
        m = fmaxf(m, __shfl_xor(m, 32));
        if (quad == 0)
            atomicMax(&keyA[b * SEQA + s0 + wc * 64 + 16 * j + l15], enc_key(m));
    }
    // keyB[t]: max over s (in-lane j; cross-l15)
#pragma unroll
    for (int i = 0; i < 4; ++i)
#pragma unroll
        for (int r = 0; r < 4; ++r) {
            float m = fmaxf(fmaxf(acc[i][0][r], acc[i][1][r]), fmaxf(acc[i][2][r], acc[i][3][r]));
            m = fmaxf(m, __shfl_xor(m, 1));
            m = fmaxf(m, __shfl_xor(m, 2));
            m = fmaxf(m, __shfl_xor(m, 4));
            m = fmaxf(m, __shfl_xor(m, 8));
            if (l15 == 0)
                atomicMax(&keyB[b * SEQB + t0 + wr * 64 + 16 * i + quad * 4 + r], enc_key(m));
        }
}

// ---- k3: softmax over per-token maxes ----
__global__ __launch_bounds__(256) void k3_softmax(const unsigned* __restrict__ keyA,
                                                  const unsigned* __restrict__ keyB,
                                                  float* __restrict__ scoreA,
                                                  float* __restrict__ scoreB) {
    const int b = blockIdx.x;
    const bool isA = (blockIdx.y == 0);
    const unsigned* keys = isA ? (keyA + b * SEQA) : (keyB + b * SEQB);
    float* score = isA ? (scoreA + b * SEQA) : (scoreB + b * SEQB);
    __shared__ float sh[4];
    const int tid = threadIdx.x;
    float m[4];
    float mx = -INFINITY;
#pragma unroll
    for (int k = 0; k < 4; k++) {
        m[k] = dec_key(keys[tid + 256 * k]);
        mx = fmaxf(mx, m[k]);
    }
#pragma unroll
    for (int o = 32; o > 0; o >>= 1) mx = fmaxf(mx, __shfl_down(mx, o, 64));
    if ((tid & 63) == 0) sh[tid >> 6] = mx;
    __syncthreads();
    mx = fmaxf(fmaxf(sh[0], sh[1]), fmaxf(sh[2], sh[3]));
    __syncthreads();
    float e[4];
    float sum = 0.f;
#pragma unroll
    for (int k = 0; k < 4; k++) { e[k] = expf(m[k] - mx); sum += e[k]; }
#pragma unroll
    for (int o = 32; o > 0; o >>= 1) sum += __shfl_down(sum, o, 64);
    if ((tid & 63) == 0) sh[tid >> 6] = sum;
    __syncthreads();
    sum = sh[0] + sh[1] + sh[2] + sh[3];
    float inv = 1.0f / sum;
#pragma unroll
    for (int k = 0; k < 4; k++) score[tid + 256 * k] = e[k] * inv;
}

// ---- k4: out[b,d] = sum_s X[b,d,s] * score[b,s]  (fp32, one wave per row) ----
__global__ __launch_bounds__(256) void k4_out(const float* __restrict__ A,
                                              const float* __restrict__ B,
                                              const float* __restrict__ scoreA,
                                              const float* __restrict__ scoreB,
                                              float* __restrict__ out) {
    const int which = blockIdx.y;
    const int row = blockIdx.x * 4 + (threadIdx.x >> 6);
    const int lane = threadIdx.x & 63;
    const float* X = which ? B : A;
    const float* S = which ? scoreB : scoreA;
    const int b = row / DIM;
    const float4* xr = (const float4*)(X + (size_t)row * SEQA);
    const float4* sr = (const float4*)(S + (size_t)b * SEQA);
    float acc = 0.f;
#pragma unroll
    for (int q = lane; q < SEQA / 4; q += 64) {
        float4 x = xr[q];
        float4 s = sr[q];
        acc += x.x * s.x + x.y * s.y + x.z * s.z + x.w * s.w;
    }
#pragma unroll
    for (int o = 32; o > 0; o >>= 1) acc += __shfl_down(acc, o, 64);
    if (lane == 0) out[which * (BSZ * DIM) + row] = acc;
}

extern "C" void kernel_launch(void* const* d_in, const int* in_sizes, int n_in,
                              void* d_out, int out_size, void* d_ws, size_t ws_size,
                              hipStream_t stream) {
    const float* A   = (const float*)d_in[0];  // (16,768,1024)
    const float* B   = (const float*)d_in[1];  // (16,768,1024)
    const float* msk = (const float*)d_in[2];  // (16,1024,1024)
    const float* U   = (const float*)d_in[3];  // (768,768)
    float* out = (float*)d_out;

    char* ws = (char*)d_ws;
    unsigned char* At = (unsigned char*)ws;                   // 12,582,912
    unsigned char* Bt = (unsigned char*)(ws + 12582912);      // 12,582,912
    unsigned char* Ct = (unsigned char*)(ws + 25165824);      // 12,582,912
    unsigned char* Ut = (unsigned char*)(ws + 37748736);      //    589,824
    unsigned* keyA   = (unsigned*)(ws + 38338560);
    unsigned* keyB   = (unsigned*)(ws + 38404096);
    float*    scoreA = (float*)   (ws + 38469632);
    float*    scoreB = (float*)   (ws + 38535168);

    t_cast_U<<<dim3(DIM / 64, DIM / 64, 1), 256, 0, stream>>>(U, Ut, keyA, keyB);
    t_cast_AB<<<dim3(SEQA / 64, DIM / 64, 2 * BSZ), 256, 0, stream>>>(A, B, At, Bt);
    // 128^2 tiles, 4 waves, 3 blocks/CU (cross-block latency hiding)
    k1_ua<<<dim3(SEQA / 128, DIM / 128, BSZ), 256, 0, stream>>>(At, Ut, Ct);
    k2_align<<<dim3(SEQB / 128, SEQA / 128, BSZ), 256, 0, stream>>>(Ct, Bt, msk, keyA, keyB);
    k3_softmax<<<dim3(BSZ, 2), 256, 0, stream>>>(keyA, keyB, scoreA, scoreB);
    k4_out<<<dim3(BSZ * DIM / 4, 2), 256, 0, stream>>>(A, B, scoreA, scoreB, out);
}

// Round 5
// 237.254 us; speedup vs baseline: 1.0746x; 1.0304x over previous
//
#include <hip/hip_runtime.h>
#include <math.h>

#define BSZ  16
#define DIM  768
#define SEQA 1024
#define SEQB 1024

typedef float f32x4 __attribute__((ext_vector_type(4)));
typedef long long llong;

__device__ inline void gload_lds16(const void* g, void* l) {
    __builtin_amdgcn_global_load_lds(
        (const __attribute__((address_space(1))) void*)g,
        (__attribute__((address_space(3))) void*)l, 16, 0, 0);
}

// ---- float <-> order-preserving uint key (atomicMax on floats) ----
__device__ inline unsigned enc_key(float f) {
    unsigned u = __float_as_uint(f);
    return (u & 0x80000000u) ? ~u : (u | 0x80000000u);
}
__device__ inline float dec_key(unsigned k) {
    return (k & 0x80000000u) ? __uint_as_float(k ^ 0x80000000u) : __uint_as_float(~k);
}

// ---- fp8 e4m3 (OCP) pack helpers ----
__device__ inline unsigned pk4_fp8(float a, float b, float c, float d) {
    int v = 0;
    v = __builtin_amdgcn_cvt_pk_fp8_f32(a, b, v, false);
    v = __builtin_amdgcn_cvt_pk_fp8_f32(c, d, v, true);
    return (unsigned)v;
}
__device__ inline unsigned char f2fp8(float a) {
    return (unsigned char)(__builtin_amdgcn_cvt_pk_fp8_f32(a, a, 0, false) & 0xFF);
}

// tanh via hardware exp: exact 1.0f in saturation, ~1e-6 error mid-range
__device__ inline float fast_tanh(float x) {
    float ax = fabsf(x);
    float u = __expf(-2.0f * ax);
    float th = __fdividef(1.0f - u, 1.0f + u);
    return copysignf(th, x);
}

// ---- prepass: X[b][DIM][SEQ] f32 -> Xt[b][SEQ][DIM] fp8 for A (z<16) and B (z>=16) ----
__global__ __launch_bounds__(256) void t_cast_AB(const float* __restrict__ A,
                                                 const float* __restrict__ B,
                                                 unsigned char* __restrict__ At,
                                                 unsigned char* __restrict__ Bt) {
    __shared__ float tl[64][68];
    const int z = blockIdx.z;
    const float* X = (z < BSZ) ? A : B;
    unsigned char* Y = (z < BSZ) ? At : Bt;
    const int b = z & 15;
    const int d0 = blockIdx.y * 64;
    const int s0 = blockIdx.x * 64;
    const int tid = threadIdx.x;
    const int rr = tid >> 4, c4 = tid & 15;  // float4 loader coords
    const float* Xb = X + ((size_t)b * DIM + d0) * SEQA + s0;
#pragma unroll
    for (int i = 0; i < 4; i++) {
        int row = i * 16 + rr;
        float4 v = *(const float4*)&Xb[(size_t)row * SEQA + c4 * 4];
        *(float4*)&tl[row][c4 * 4] = v;
    }
    __syncthreads();
    unsigned char* Yb = Y + ((size_t)b * SEQA + s0) * DIM + d0;
    const int m = tid & 15, sl = tid >> 4;
#pragma unroll
    for (int i = 0; i < 4; i++) {
        int s = sl + 16 * i;
        unsigned v = pk4_fp8(tl[4 * m + 0][s], tl[4 * m + 1][s], tl[4 * m + 2][s], tl[4 * m + 3][s]);
        *(unsigned*)&Yb[(size_t)s * DIM + 4 * m] = v;
    }
}

// ---- prepass: U[d][e] f32 -> Ut[e][d] fp8 ; also init max-keys ----
__global__ __launch_bounds__(256) void t_cast_U(const float* __restrict__ U,
                                                unsigned char* __restrict__ Ut,
                                                unsigned* __restrict__ keyA,
                                                unsigned* __restrict__ keyB) {
    __shared__ float tl[64][68];
    const int d0 = blockIdx.y * 64;
    const int e0 = blockIdx.x * 64;
    const int tid = threadIdx.x;
    const int bid = blockIdx.y * gridDim.x + blockIdx.x;
    if (bid < 64) {
        int i = bid * 256 + tid;
        keyA[i] = 0u;
        keyB[i] = 0u;
    }
    const int rr = tid >> 4, c4 = tid & 15;
#pragma unroll
    for (int i = 0; i < 4; i++) {
        int row = i * 16 + rr;
        float4 v = *(const float4*)&U[(size_t)(d0 + row) * DIM + e0 + c4 * 4];
        *(float4*)&tl[row][c4 * 4] = v;
    }
    __syncthreads();
    const int m = tid & 15, sl = tid >> 4;
#pragma unroll
    for (int i = 0; i < 4; i++) {
        int e = sl + 16 * i;
        unsigned v = pk4_fp8(tl[4 * m + 0][e], tl[4 * m + 1][e], tl[4 * m + 2][e], tl[4 * m + 3][e]);
        *(unsigned*)&Ut[(size_t)(e0 + e) * DIM + d0 + 4 * m] = v;
    }
}

// Stage a (nwaves*32)-row x 128-byte tile (rows of `src`, pitch DIM) into LDS with
// granule-XOR swizzle. Wave `wid` covers rows [wid*32, wid*32+32). 4 gloads/wave.
__device__ inline void stage_tile(const unsigned char* __restrict__ src, int row0,
                                  int kbyte0, unsigned char* lds, int wid, int lane) {
    const int r8 = lane >> 3;              // row within 8-row group
    const int g  = lane & 7;               // dest granule slot
    const int gg = g ^ (r8 & 7);           // source granule (XOR swizzle)
#pragma unroll
    for (int t = 0; t < 4; ++t) {
        int row = row0 + wid * 32 + t * 8 + r8;
        gload_lds16(src + (size_t)row * DIM + kbyte0 + gg * 16,
                    lds + (wid * 32 + t * 8) * 128 + lane * 16);
    }
}

// Read an 8-byte fp8 fragment (16 rows x k-slice) with matching XOR un-swizzle.
// rowbase multiple of 16; h = 32-byte k-slice index (0..3).
__device__ inline llong frag_read(const unsigned char* lds, int rowbase, int l15,
                                  int quad, int h) {
    int gg = 2 * h + (quad >> 1);
    int off = (rowbase + l15) * 128 + ((gg ^ (l15 & 7)) << 4) + (quad & 1) * 8;
    return *(const llong*)(lds + off);
}

// ---- k1: Ct[b][s][e] = sum_d At[b][s][d] * Ut[e][d]  (fp8 MFMA, 128x128, BK=128) ----
// 768 blocks = exactly 3/CU at 3-resident: balanced single round (m97/m114 regime).
__global__ __launch_bounds__(256, 3) void k1_ua(const unsigned char* __restrict__ At,
                                                const unsigned char* __restrict__ Ut,
                                                unsigned char* __restrict__ Ct) {
    __shared__ __align__(16) unsigned char As[128 * 128];
    __shared__ __align__(16) unsigned char Us[128 * 128];
    const int b  = blockIdx.z;
    const int s0 = blockIdx.x * 128;
    const int e0 = blockIdx.y * 128;
    const int tid = threadIdx.x;
    const int lane = tid & 63;
    const int wid = tid >> 6;
    const int wr = wid >> 1, wc = wid & 1;
    const int quad = lane >> 4, l15 = lane & 15;

    const unsigned char* Atb = At + (size_t)b * SEQA * DIM;
    f32x4 acc[4][4] = {};

    for (int d0 = 0; d0 < DIM; d0 += 128) {
        stage_tile(Atb + (size_t)s0 * DIM, 0, d0, As, wid, lane);
        stage_tile(Ut + (size_t)e0 * DIM, 0, d0, Us, wid, lane);
        __syncthreads();
#pragma unroll
        for (int h = 0; h < 4; ++h) {
            llong av[4], bv[4];
#pragma unroll
            for (int i = 0; i < 4; ++i) av[i] = frag_read(As, wr * 64 + 16 * i, l15, quad, h);
#pragma unroll
            for (int j = 0; j < 4; ++j) bv[j] = frag_read(Us, wc * 64 + 16 * j, l15, quad, h);
#pragma unroll
            for (int i = 0; i < 4; ++i)
#pragma unroll
                for (int j = 0; j < 4; ++j)
                    acc[i][j] = __builtin_amdgcn_mfma_f32_16x16x32_fp8_fp8(av[i], bv[j], acc[i][j], 0, 0, 0);
        }
        __syncthreads();
    }
    // D: M(s) = wr*64+16i+quad*4+r, N(e) = wc*64+16j+l15 -> byte stores, 16B segments
    unsigned char* Cb = Ct + (size_t)b * SEQA * DIM;
#pragma unroll
    for (int i = 0; i < 4; ++i)
#pragma unroll
        for (int j = 0; j < 4; ++j) {
            int e_g = e0 + wc * 64 + 16 * j + l15;
#pragma unroll
            for (int r = 0; r < 4; ++r) {
                int s_g = s0 + wr * 64 + 16 * i + quad * 4 + r;
                Cb[(size_t)s_g * DIM + e_g] = f2fp8(acc[i][j][r]);
            }
        }
}

// ---- k2: align^T tile = tanh(Bt x Ct) + msk; fused max -> atomic keys ----
// Grid = 1024 blocks = 4/CU. Previous (256,3) ran 2 rounds {3 blocks, 1 block}
// (measured occupancy 21% = avg of 12 and 4 waves) — the 1-block round had no
// cross-block latency hiding. (256,4) packs one balanced round: needs arch
// VGPR <= 64 (+64 acc = 128 total), hence the register-diet epilogue below.
__global__ __launch_bounds__(256, 4) void k2_align(const unsigned char* __restrict__ Ct,
                                                   const unsigned char* __restrict__ Bt,
                                                   const float* __restrict__ msk,
                                                   unsigned* __restrict__ keyA,
                                                   unsigned* __restrict__ keyB) {
    __shared__ __align__(16) unsigned char Cs[128 * 128];
    __shared__ __align__(16) unsigned char Bs[128 * 128];
    const int b  = blockIdx.z;
    const int t0 = blockIdx.x * 128;
    const int s0 = blockIdx.y * 128;
    const int tid = threadIdx.x;
    const int lane = tid & 63;
    const int wid = tid >> 6;
    const int wr = wid >> 1, wc = wid & 1;
    const int quad = lane >> 4, l15 = lane & 15;

    f32x4 acc[4][4] = {};

    for (int e0 = 0; e0 < DIM; e0 += 128) {
        stage_tile(Ct + (size_t)(b * SEQA + s0) * DIM, 0, e0, Cs, wid, lane);
        stage_tile(Bt + (size_t)(b * SEQB + t0) * DIM, 0, e0, Bs, wid, lane);
        __syncthreads();
#pragma unroll
        for (int h = 0; h < 4; ++h) {
            llong av[4], bv[4];
#pragma unroll
            for (int i = 0; i < 4; ++i) av[i] = frag_read(Bs, wr * 64 + 16 * i, l15, quad, h);
#pragma unroll
            for (int j = 0; j < 4; ++j) bv[j] = frag_read(Cs, wc * 64 + 16 * j, l15, quad, h);
#pragma unroll
            for (int i = 0; i < 4; ++i)
#pragma unroll
                for (int j = 0; j < 4; ++j)
                    acc[i][j] = __builtin_amdgcn_mfma_f32_16x16x32_fp8_fp8(av[i], bv[j], acc[i][j], 0, 0, 0);
        }
        __syncthreads();
    }

    // epilogue (register diet): one float4 mask load per (i,j), applied in place
    const float* Mb = msk + (size_t)b * SEQA * SEQB;
#pragma unroll
    for (int j = 0; j < 4; ++j) {
        int s_g = s0 + wc * 64 + 16 * j + l15;
#pragma unroll
        for (int i = 0; i < 4; ++i) {
            int t_g = t0 + wr * 64 + 16 * i + quad * 4;
            float4 mvv = *(const float4*)&Mb[(size_t)s_g * SEQB + t_g];
            acc[i][j][0] = fast_tanh(acc[i][j][0]) + mvv.x;
            acc[i][j][1] = fast_tanh(acc[i][j][1]) + mvv.y;
            acc[i][j][2] = fast_tanh(acc[i][j][2]) + mvv.z;
            acc[i][j][3] = fast_tanh(acc[i][j][3]) + mvv.w;
        }
    }
    // keyA[s]: max over t (in-lane i,r; cross-quad)
#pragma unroll
    for (int j = 0; j < 4; ++j) {
        float m = -INFINITY;
#pragma unroll
        for (int i = 0; i < 4; ++i)
#pragma unroll
            for (int r = 0; r < 4; ++r) m = fmaxf(m, acc[i][j][r]);
        m = fmaxf(m, __shfl_xor(m, 16));
        m = fmaxf(m, __shfl_xor(m, 32));
        if (quad == 0)
            atomicMax(&keyA[b * SEQA + s0 + wc * 64 + 16 * j + l15], enc_key(m));
    }
    // keyB[t]: max over s (in-lane j; cross-l15)
#pragma unroll
    for (int i = 0; i < 4; ++i)
#pragma unroll
        for (int r = 0; r < 4; ++r) {
            float m = fmaxf(fmaxf(acc[i][0][r], acc[i][1][r]), fmaxf(acc[i][2][r], acc[i][3][r]));
            m = fmaxf(m, __shfl_xor(m, 1));
            m = fmaxf(m, __shfl_xor(m, 2));
            m = fmaxf(m, __shfl_xor(m, 4));
            m = fmaxf(m, __shfl_xor(m, 8));
            if (l15 == 0)
                atomicMax(&keyB[b * SEQB + t0 + wr * 64 + 16 * i + quad * 4 + r], enc_key(m));
        }
}

// ---- k3: softmax over per-token maxes ----
__global__ __launch_bounds__(256) void k3_softmax(const unsigned* __restrict__ keyA,
                                                  const unsigned* __restrict__ keyB,
                                                  float* __restrict__ scoreA,
                                                  float* __restrict__ scoreB) {
    const int b = blockIdx.x;
    const bool isA = (blockIdx.y == 0);
    const unsigned* keys = isA ? (keyA + b * SEQA) : (keyB + b * SEQB);
    float* score = isA ? (scoreA + b * SEQA) : (scoreB + b * SEQB);
    __shared__ float sh[4];
    const int tid = threadIdx.x;
    float m[4];
    float mx = -INFINITY;
#pragma unroll
    for (int k = 0; k < 4; k++) {
        m[k] = dec_key(keys[tid + 256 * k]);
        mx = fmaxf(mx, m[k]);
    }
#pragma unroll
    for (int o = 32; o > 0; o >>= 1) mx = fmaxf(mx, __shfl_down(mx, o, 64));
    if ((tid & 63) == 0) sh[tid >> 6] = mx;
    __syncthreads();
    mx = fmaxf(fmaxf(sh[0], sh[1]), fmaxf(sh[2], sh[3]));
    __syncthreads();
    float e[4];
    float sum = 0.f;
#pragma unroll
    for (int k = 0; k < 4; k++) { e[k] = expf(m[k] - mx); sum += e[k]; }
#pragma unroll
    for (int o = 32; o > 0; o >>= 1) sum += __shfl_down(sum, o, 64);
    if ((tid & 63) == 0) sh[tid >> 6] = sum;
    __syncthreads();
    sum = sh[0] + sh[1] + sh[2] + sh[3];
    float inv = 1.0f / sum;
#pragma unroll
    for (int k = 0; k < 4; k++) score[tid + 256 * k] = e[k] * inv;
}

// ---- k4: out[b,d] = sum_s X[b,d,s] * score[b,s]  (fp32, one wave per row) ----
__global__ __launch_bounds__(256) void k4_out(const float* __restrict__ A,
                                              const float* __restrict__ B,
                                              const float* __restrict__ scoreA,
                                              const float* __restrict__ scoreB,
                                              float* __restrict__ out) {
    const int which = blockIdx.y;
    const int row = blockIdx.x * 4 + (threadIdx.x >> 6);
    const int lane = threadIdx.x & 63;
    const float* X = which ? B : A;
    const float* S = which ? scoreB : scoreA;
    const int b = row / DIM;
    const float4* xr = (const float4*)(X + (size_t)row * SEQA);
    const float4* sr = (const float4*)(S + (size_t)b * SEQA);
    float acc = 0.f;
#pragma unroll
    for (int q = lane; q < SEQA / 4; q += 64) {
        float4 x = xr[q];
        float4 s = sr[q];
        acc += x.x * s.x + x.y * s.y + x.z * s.z + x.w * s.w;
    }
#pragma unroll
    for (int o = 32; o > 0; o >>= 1) acc += __shfl_down(acc, o, 64);
    if (lane == 0) out[which * (BSZ * DIM) + row] = acc;
}

extern "C" void kernel_launch(void* const* d_in, const int* in_sizes, int n_in,
                              void* d_out, int out_size, void* d_ws, size_t ws_size,
                              hipStream_t stream) {
    const float* A   = (const float*)d_in[0];  // (16,768,1024)
    const float* B   = (const float*)d_in[1];  // (16,768,1024)
    const float* msk = (const float*)d_in[2];  // (16,1024,1024)
    const float* U   = (const float*)d_in[3];  // (768,768)
    float* out = (float*)d_out;

    char* ws = (char*)d_ws;
    unsigned char* At = (unsigned char*)ws;                   // 12,582,912
    unsigned char* Bt = (unsigned char*)(ws + 12582912);      // 12,582,912
    unsigned char* Ct = (unsigned char*)(ws + 25165824);      // 12,582,912
    unsigned char* Ut = (unsigned char*)(ws + 37748736);      //    589,824
    unsigned* keyA   = (unsigned*)(ws + 38338560);
    unsigned* keyB   = (unsigned*)(ws + 38404096);
    float*    scoreA = (float*)   (ws + 38469632);
    float*    scoreB = (float*)   (ws + 38535168);

    t_cast_U<<<dim3(DIM / 64, DIM / 64, 1), 256, 0, stream>>>(U, Ut, keyA, keyB);
    t_cast_AB<<<dim3(SEQA / 64, DIM / 64, 2 * BSZ), 256, 0, stream>>>(A, B, At, Bt);
    // k1: 768 blocks = 3/CU balanced at 3-resident
    k1_ua<<<dim3(SEQA / 128, DIM / 128, BSZ), 256, 0, stream>>>(At, Ut, Ct);
    // k2: 1024 blocks = 4/CU, now 4-resident (one balanced round)
    k2_align<<<dim3(SEQB / 128, SEQA / 128, BSZ), 256, 0, stream>>>(Ct, Bt, msk, keyA, keyB);
    k3_softmax<<<dim3(BSZ, 2), 256, 0, stream>>>(keyA, keyB, scoreA, scoreB);
    k4_out<<<dim3(BSZ * DIM / 4, 2), 256, 0, stream>>>(A, B, scoreA, scoreB, out);
}